// Round 15
// baseline (36.547 us; speedup 1.0000x reference)
//
#include <hip/hip_runtime.h>
#include <hip/hip_bf16.h>

#define B_   4
#define C_   128
#define H_   64
#define W_   64
#define HW_  4096
#define KW_  7
#define PAD_ 3
#define G_   8
#define CPG_ 16

#define CPAD 136   // f16 elems per LDS row in proj; row stride 272 B

// attn LDS geometry
#define TS    16
#define HALO  22
#define NHP   (HALO*HALO)
#define LP    24          // ushorts per pixel (48 B): balanced banks, 16B-aligned

typedef _Float16 f16x8 __attribute__((ext_vector_type(8)));
typedef _Float16 f16x2 __attribute__((ext_vector_type(2)));
typedef _Float16 h2    __attribute__((ext_vector_type(2)));
typedef float    f32x4 __attribute__((ext_vector_type(4)));

static __device__ __forceinline__ unsigned short f2h(float f) {
    _Float16 h = (_Float16)f;
    union { _Float16 h; unsigned short u; } cv; cv.h = h;
    return cv.u;
}

#if defined(__has_builtin)
#if __has_builtin(__builtin_amdgcn_fdot2)
#define HAVE_FDOT2 1
#endif
#endif

// ---------------------------------------------------------------------------
// Kernel A: fp16-MFMA 1x1 conv projections, O-HALF SPLIT (VERBATIM round-14).
// grid: (64 p-tiles, B, 6 = 3 matrices x 2 o-halves), block 256 (4 waves).
// Output: fp16, GROUP-PLANAR qkv16[m][b][g][pix][16] (pixel stride 32 B).
// ---------------------------------------------------------------------------
__global__ __launch_bounds__(256) void proj_mfma(
    const float* __restrict__ x,
    const float* __restrict__ Wq,
    const float* __restrict__ Wk,
    const float* __restrict__ Wv,
    unsigned short* __restrict__ qkv16)
{
    const int ptile = blockIdx.x;        // 0..63
    const int b     = blockIdx.y;
    const int mz    = blockIdx.z;        // 0..5
    const int m     = mz >> 1;
    const int oh    = mz & 1;            // o-half: channels oh*64 .. oh*64+63
    const float* Wm = (m == 0) ? Wq : ((m == 1) ? Wk : Wv);
    const float* xb = x + (size_t)b * C_ * HW_;
    unsigned short* y = qkv16 + ((size_t)(m * B_ + b)) * HW_ * C_;
    const int p0  = ptile * 64;
    const int tid = threadIdx.x;

    __shared__ unsigned short wls[64 * CPAD];   // [o-local][c] f16
    __shared__ unsigned short xls[64 * CPAD];   // [p][c] f16 (transposed X)

    // stage W half: 64 o x 128 c (8 iters)
    #pragma unroll
    for (int it = 0; it < 8; ++it) {
        const int idx = tid + it * 256;
        const int o   = idx >> 5;            // 0..63 local row
        const int c4  = (idx & 31) * 4;
        const float4 w4 = *(const float4*)(Wm + (size_t)(oh * 64 + o) * C_ + c4);
        ushort4 hh;
        hh.x = f2h(w4.x); hh.y = f2h(w4.y); hh.z = f2h(w4.z); hh.w = f2h(w4.w);
        *(ushort4*)(&wls[o * CPAD + c4]) = hh;
    }
    // stage X^T: 4c x 4p micro-transpose blocks (2 iters)
    #pragma unroll
    for (int it = 0; it < 2; ++it) {
        const int idx = tid + it * 256;
        const int pq  = (idx & 15) * 4;
        const int cq  = (idx >> 4) * 4;
        const float* xp = xb + (size_t)cq * HW_ + p0 + pq;
        const float4 r0 = *(const float4*)(xp);
        const float4 r1 = *(const float4*)(xp + HW_);
        const float4 r2 = *(const float4*)(xp + 2 * HW_);
        const float4 r3 = *(const float4*)(xp + 3 * HW_);
        ushort4 hh;
        hh.x = f2h(r0.x); hh.y = f2h(r1.x); hh.z = f2h(r2.x); hh.w = f2h(r3.x);
        *(ushort4*)(&xls[(pq + 0) * CPAD + cq]) = hh;
        hh.x = f2h(r0.y); hh.y = f2h(r1.y); hh.z = f2h(r2.y); hh.w = f2h(r3.y);
        *(ushort4*)(&xls[(pq + 1) * CPAD + cq]) = hh;
        hh.x = f2h(r0.z); hh.y = f2h(r1.z); hh.z = f2h(r2.z); hh.w = f2h(r3.z);
        *(ushort4*)(&xls[(pq + 2) * CPAD + cq]) = hh;
        hh.x = f2h(r0.w); hh.y = f2h(r1.w); hh.z = f2h(r2.w); hh.w = f2h(r3.w);
        *(ushort4*)(&xls[(pq + 3) * CPAD + cq]) = hh;
    }
    __syncthreads();

    const int wv   = tid >> 6;     // wave id: owns 16 pixels
    const int lane = tid & 63;
    const int row  = lane & 15;
    const int kq   = lane >> 4;

    f32x4 acc[4];
    #pragma unroll
    for (int ot = 0; ot < 4; ++ot)
        acc[ot] = (f32x4){0.f, 0.f, 0.f, 0.f};

    #pragma unroll
    for (int ks = 0; ks < 4; ++ks) {
        const int cb = ks * 32 + kq * 8;
        const f16x8 bfrag = *(const f16x8*)(&xls[(wv * 16 + row) * CPAD + cb]);
        #pragma unroll
        for (int ot = 0; ot < 4; ++ot) {
            const f16x8 afrag = *(const f16x8*)(&wls[(ot * 16 + row) * CPAD + cb]);
            acc[ot] = __builtin_amdgcn_mfma_f32_16x16x32_f16(afrag, bfrag, acc[ot], 0, 0, 0);
        }
    }

    // D: lane holds D[o-local = ot*16 + kq*4 + reg][p = p0 + wv*16 + row]
    const int p = p0 + wv * 16 + row;
    #pragma unroll
    for (int ot = 0; ot < 4; ++ot) {
        const int got = oh * 4 + ot;
        ushort4 hh;
        hh.x = f2h(acc[ot][0]); hh.y = f2h(acc[ot][1]);
        hh.z = f2h(acc[ot][2]); hh.w = f2h(acc[ot][3]);
        *(ushort4*)(y + ((size_t)got * HW_ + p) * CPG_ + kq * 4) = hh;
    }
}

// ---------------------------------------------------------------------------
// Kernel B: grouped 7x7 local attention. K halo staged in LDS (score phase);
// V read DIRECTLY FROM GLOBAL in the PV phase (L1-resident 15.5 KB halo) --
// splits the two operand streams across the LDS and vector-L1 pipes.
// Packed-f16 PV accumulation. grid: (16 tiles, G, B), block 256.
// ---------------------------------------------------------------------------
__global__ __launch_bounds__(256) void attn_kernel(
    const unsigned short* __restrict__ qkv16,
    const float* __restrict__ rel_h,   // [64][7]
    const float* __restrict__ rel_w,   // [64][7]
    float* __restrict__ out)           // [B][128][64][64]
{
    const int tile = blockIdx.x;
    const int g    = blockIdx.y;
    const int b    = blockIdx.z;
    const int h0   = (tile >> 2) * TS;
    const int w0   = (tile & 3) * TS;
    const int c0   = g * CPG_;

    __shared__ unsigned short kls[NHP * LP];    // K halo only: 23.2 KB

    const size_t gplane = (size_t)HW_ * CPG_;
    const size_t mplane = (size_t)B_ * G_ * gplane;
    const unsigned short* qb = qkv16              + ((size_t)b * G_ + g) * gplane;
    const unsigned short* kb = qkv16 + mplane     + ((size_t)b * G_ + g) * gplane;
    const unsigned short* vb = qkv16 + 2 * mplane + ((size_t)b * G_ + g) * gplane;

    const int tid = threadIdx.x;
    const int pw  = tid & 15;
    const int ph  = tid >> 4;
    const int pix = (h0 + ph) * W_ + (w0 + pw);

    // q fragment first (independent of staging -> overlaps)
    const f16x8 q0 = *(const f16x8*)(qb + (size_t)pix * CPG_);
    const f16x8 q1 = *(const f16x8*)(qb + (size_t)pix * CPG_ + 8);

    // stage K halo: 968 x 16B chunks, coalesced, zero-fill OOB
    #pragma unroll
    for (int it = 0; it < 4; ++it) {
        const int idx = tid + it * 256;
        if (idx < NHP * 2) {
            const int lp   = idx >> 1;
            const int half = idx & 1;
            const int hy   = h0 + lp / HALO - PAD_;
            const int hx   = w0 + lp % HALO - PAD_;
            f16x8 val = (f16x8)(_Float16)0.f;
            if ((unsigned)hy < (unsigned)H_ && (unsigned)hx < (unsigned)W_)
                val = *(const f16x8*)(kb + (size_t)(hy * W_ + hx) * CPG_ + half * 8);
            *(f16x8*)(&kls[lp * LP + half * 8]) = val;
        }
    }

    float qv[CPG_];
    #pragma unroll
    for (int c = 0; c < 8; ++c) { qv[c] = (float)q0[c]; qv[8 + c] = (float)q1[c]; }

    // rel score
    const bool useH = (g < 4);
    const float* rp = useH ? (rel_h + c0 * KW_) : (rel_w + (c0 - 64) * KW_);
    float rel[KW_];
    #pragma unroll
    for (int t = 0; t < KW_; ++t) {
        float r = 0.f;
        #pragma unroll
        for (int c = 0; c < CPG_; ++c) r += qv[c] * rp[c * KW_ + t];
        rel[t] = r;
    }

    __syncthreads();

    // scores: all 49 positions (OOB k == 0 -> score = rel, matches zero-pad)
    float s[KW_ * KW_];
    float smax = -1e30f;
    #pragma unroll
    for (int i = 0; i < KW_; ++i) {
        #pragma unroll
        for (int j = 0; j < KW_; ++j) {
            const unsigned short* kp = &kls[((ph + i) * HALO + (pw + j)) * LP];
            const f16x8 k0 = *(const f16x8*)(kp);
            const f16x8 k1 = *(const f16x8*)(kp + 8);
            float sc = useH ? rel[i] : rel[j];
#ifdef HAVE_FDOT2
            #pragma unroll
            for (int t = 0; t < 4; ++t) {
                sc = __builtin_amdgcn_fdot2((h2){q0[2*t], q0[2*t+1]},
                                            (h2){k0[2*t], k0[2*t+1]}, sc, false);
                sc = __builtin_amdgcn_fdot2((h2){q1[2*t], q1[2*t+1]},
                                            (h2){k1[2*t], k1[2*t+1]}, sc, false);
            }
#else
            #pragma unroll
            for (int c = 0; c < 8; ++c)
                sc += qv[c] * (float)k0[c] + qv[8 + c] * (float)k1[c];
#endif
            s[i * KW_ + j] = sc;
            smax = fmaxf(smax, sc);
        }
    }

    // softmax
    float denom = 0.f;
    #pragma unroll
    for (int n = 0; n < KW_ * KW_; ++n) {
        s[n] = __expf(s[n] - smax);
        denom += s[n];
    }
    const float rdenom = 1.f / denom;

    // output = attn . V  -- V straight from global (L1-resident halo),
    // packed f16x2 accumulation; OOB positions skipped (V==0 contribution).
    f16x2 acch[8];
    #pragma unroll
    for (int c = 0; c < 8; ++c) acch[c] = (f16x2){(_Float16)0.f, (_Float16)0.f};

    #pragma unroll
    for (int i = 0; i < KW_; ++i) {
        const int y = h0 + ph + i - PAD_;
        if ((unsigned)y >= (unsigned)H_) continue;
        const unsigned short* vrow = vb + (size_t)(y * W_) * CPG_;
        #pragma unroll
        for (int j = 0; j < KW_; ++j) {
            const int x = w0 + pw + j - PAD_;
            if ((unsigned)x >= (unsigned)W_) continue;
            const _Float16 ah = (_Float16)s[i * KW_ + j];
            const f16x2 av = {ah, ah};
            const unsigned short* vp = vrow + (size_t)x * CPG_;
            const f16x8 v0 = *(const f16x8*)(vp);
            const f16x8 v1 = *(const f16x8*)(vp + 8);
            #pragma unroll
            for (int c = 0; c < 4; ++c) {
                const f16x2 p0v = {v0[2 * c], v0[2 * c + 1]};
                const f16x2 p1v = {v1[2 * c], v1[2 * c + 1]};
                acch[c]     += av * p0v;
                acch[4 + c] += av * p1v;
            }
        }
    }

    float* ob = out + ((size_t)b * C_ + c0) * HW_;
    #pragma unroll
    for (int c = 0; c < 8; ++c) {
        ob[(size_t)(2 * c)     * HW_ + pix] = (float)acch[c][0] * rdenom;
        ob[(size_t)(2 * c + 1) * HW_ + pix] = (float)acch[c][1] * rdenom;
    }
}

// ---------------------------------------------------------------------------
extern "C" void kernel_launch(void* const* d_in, const int* in_sizes, int n_in,
                              void* d_out, int out_size, void* d_ws, size_t ws_size,
                              hipStream_t stream) {
    const float* x     = (const float*)d_in[0];
    const float* Wq    = (const float*)d_in[1];
    const float* Wk    = (const float*)d_in[2];
    const float* Wv    = (const float*)d_in[3];
    const float* rel_h = (const float*)d_in[4];
    const float* rel_w = (const float*)d_in[5];
    unsigned short* ws = (unsigned short*)d_ws;  // fp16 qkv [3][B][G][4096][16] = 12 MB
    float* out = (float*)d_out;

    dim3 gA(HW_ / 64, B_, 6);
    proj_mfma<<<gA, 256, 0, stream>>>(x, Wq, Wk, Wv, ws);

    dim3 gB(16, G_, B_);
    attn_kernel<<<gB, 256, 0, stream>>>(ws, rel_h, rel_w, out);
}

// Round 16
// 31.851 us; speedup vs baseline: 1.1474x; 1.1474x over previous
//
#include <hip/hip_runtime.h>
#include <hip/hip_bf16.h>

#define B_   4
#define C_   128
#define H_   64
#define W_   64
#define HW_  4096
#define KW_  7
#define PAD_ 3
#define G_   8
#define CPG_ 16

#define CPAD 136   // f16 elems per LDS row in proj; row stride 272 B

// attn LDS geometry (round-6/10 proven)
#define TS    16
#define HALO  22
#define NHP   (HALO*HALO)
#define LP    24          // ushorts per pixel (48 B): balanced banks, 16B-aligned

typedef _Float16 f16x8 __attribute__((ext_vector_type(8)));
typedef _Float16 f16x2 __attribute__((ext_vector_type(2)));
typedef _Float16 h2    __attribute__((ext_vector_type(2)));
typedef float    f32x4 __attribute__((ext_vector_type(4)));

static __device__ __forceinline__ unsigned short f2h(float f) {
    _Float16 h = (_Float16)f;
    union { _Float16 h; unsigned short u; } cv; cv.h = h;
    return cv.u;
}

#if defined(__has_builtin)
#if __has_builtin(__builtin_amdgcn_fdot2)
#define HAVE_FDOT2 1
#endif
#endif

// ---------------------------------------------------------------------------
// Kernel A: fp16-MFMA 1x1 conv projections, O-HALF SPLIT for occupancy.
// Each block: 64 output channels x 64 pixels. LDS 34.8 KB -> 4 blocks/CU.
// grid: (64 p-tiles, B, 6 = 3 matrices x 2 o-halves), block 256 (4 waves).
// Output: fp16, GROUP-PLANAR qkv16[m][b][g][pix][16] (pixel stride 32 B).
// ---------------------------------------------------------------------------
__global__ __launch_bounds__(256) void proj_mfma(
    const float* __restrict__ x,
    const float* __restrict__ Wq,
    const float* __restrict__ Wk,
    const float* __restrict__ Wv,
    unsigned short* __restrict__ qkv16)
{
    const int ptile = blockIdx.x;        // 0..63
    const int b     = blockIdx.y;
    const int mz    = blockIdx.z;        // 0..5
    const int m     = mz >> 1;
    const int oh    = mz & 1;            // o-half: channels oh*64 .. oh*64+63
    const float* Wm = (m == 0) ? Wq : ((m == 1) ? Wk : Wv);
    const float* xb = x + (size_t)b * C_ * HW_;
    unsigned short* y = qkv16 + ((size_t)(m * B_ + b)) * HW_ * C_;
    const int p0  = ptile * 64;
    const int tid = threadIdx.x;

    __shared__ unsigned short wls[64 * CPAD];   // [o-local][c] f16
    __shared__ unsigned short xls[64 * CPAD];   // [p][c] f16 (transposed X)

    // stage W half: 64 o x 128 c (8 iters)
    #pragma unroll
    for (int it = 0; it < 8; ++it) {
        const int idx = tid + it * 256;
        const int o   = idx >> 5;            // 0..63 local row
        const int c4  = (idx & 31) * 4;
        const float4 w4 = *(const float4*)(Wm + (size_t)(oh * 64 + o) * C_ + c4);
        ushort4 hh;
        hh.x = f2h(w4.x); hh.y = f2h(w4.y); hh.z = f2h(w4.z); hh.w = f2h(w4.w);
        *(ushort4*)(&wls[o * CPAD + c4]) = hh;
    }
    // stage X^T: 4c x 4p micro-transpose blocks (2 iters)
    #pragma unroll
    for (int it = 0; it < 2; ++it) {
        const int idx = tid + it * 256;
        const int pq  = (idx & 15) * 4;
        const int cq  = (idx >> 4) * 4;
        const float* xp = xb + (size_t)cq * HW_ + p0 + pq;
        const float4 r0 = *(const float4*)(xp);
        const float4 r1 = *(const float4*)(xp + HW_);
        const float4 r2 = *(const float4*)(xp + 2 * HW_);
        const float4 r3 = *(const float4*)(xp + 3 * HW_);
        ushort4 hh;
        hh.x = f2h(r0.x); hh.y = f2h(r1.x); hh.z = f2h(r2.x); hh.w = f2h(r3.x);
        *(ushort4*)(&xls[(pq + 0) * CPAD + cq]) = hh;
        hh.x = f2h(r0.y); hh.y = f2h(r1.y); hh.z = f2h(r2.y); hh.w = f2h(r3.y);
        *(ushort4*)(&xls[(pq + 1) * CPAD + cq]) = hh;
        hh.x = f2h(r0.z); hh.y = f2h(r1.z); hh.z = f2h(r2.z); hh.w = f2h(r3.z);
        *(ushort4*)(&xls[(pq + 2) * CPAD + cq]) = hh;
        hh.x = f2h(r0.w); hh.y = f2h(r1.w); hh.z = f2h(r2.w); hh.w = f2h(r3.w);
        *(ushort4*)(&xls[(pq + 3) * CPAD + cq]) = hh;
    }
    __syncthreads();

    const int wv   = tid >> 6;     // wave id: owns 16 pixels
    const int lane = tid & 63;
    const int row  = lane & 15;
    const int kq   = lane >> 4;

    f32x4 acc[4];
    #pragma unroll
    for (int ot = 0; ot < 4; ++ot)
        acc[ot] = (f32x4){0.f, 0.f, 0.f, 0.f};

    #pragma unroll
    for (int ks = 0; ks < 4; ++ks) {
        const int cb = ks * 32 + kq * 8;
        const f16x8 bfrag = *(const f16x8*)(&xls[(wv * 16 + row) * CPAD + cb]);
        #pragma unroll
        for (int ot = 0; ot < 4; ++ot) {
            const f16x8 afrag = *(const f16x8*)(&wls[(ot * 16 + row) * CPAD + cb]);
            acc[ot] = __builtin_amdgcn_mfma_f32_16x16x32_f16(afrag, bfrag, acc[ot], 0, 0, 0);
        }
    }

    // D: lane holds D[o-local = ot*16 + kq*4 + reg][p = p0 + wv*16 + row]
    // global group = oh*4 + ot; within-group channel = kq*4 + reg.
    const int p = p0 + wv * 16 + row;
    #pragma unroll
    for (int ot = 0; ot < 4; ++ot) {
        const int got = oh * 4 + ot;
        ushort4 hh;
        hh.x = f2h(acc[ot][0]); hh.y = f2h(acc[ot][1]);
        hh.z = f2h(acc[ot][2]); hh.w = f2h(acc[ot][3]);
        *(ushort4*)(y + ((size_t)got * HW_ + p) * CPG_ + kq * 4) = hh;
    }
}

// ---------------------------------------------------------------------------
// Kernel B: grouped 7x7 local attention (round-10 structure), fdot2 scores,
// PACKED-f16 PV accumulation (v_pk_fma_f16; error suppressed by 1/den).
// grid: (16 tiles, G, B), block 256.
// ---------------------------------------------------------------------------
__global__ __launch_bounds__(256) void attn_kernel(
    const unsigned short* __restrict__ qkv16,
    const float* __restrict__ rel_h,   // [64][7]
    const float* __restrict__ rel_w,   // [64][7]
    float* __restrict__ out)           // [B][128][64][64]
{
    const int tile = blockIdx.x;
    const int g    = blockIdx.y;
    const int b    = blockIdx.z;
    const int h0   = (tile >> 2) * TS;
    const int w0   = (tile & 3) * TS;
    const int c0   = g * CPG_;

    __shared__ unsigned short kvls[2][NHP * LP];

    const size_t gplane = (size_t)HW_ * CPG_;
    const size_t mplane = (size_t)B_ * G_ * gplane;
    const unsigned short* qb = qkv16              + ((size_t)b * G_ + g) * gplane;
    const unsigned short* kb = qkv16 + mplane     + ((size_t)b * G_ + g) * gplane;
    const unsigned short* vb = qkv16 + 2 * mplane + ((size_t)b * G_ + g) * gplane;

    const int tid = threadIdx.x;
    const int pw  = tid & 15;
    const int ph  = tid >> 4;
    const int pix = (h0 + ph) * W_ + (w0 + pw);

    // q fragment first (independent of staging -> overlaps)
    const f16x8 q0 = *(const f16x8*)(qb + (size_t)pix * CPG_);
    const f16x8 q1 = *(const f16x8*)(qb + (size_t)pix * CPG_ + 8);

    // stage K and V halo: 1936 x 16B chunks, coalesced, zero-fill OOB
    #pragma unroll
    for (int it = 0; it < 8; ++it) {
        const int idx = tid + it * 256;
        if (idx < 2 * NHP * 2) {
            const int arr  = (idx >= NHP * 2) ? 1 : 0;
            const int r    = idx - arr * NHP * 2;
            const int lp   = r >> 1;
            const int half = r & 1;
            const int hy   = h0 + lp / HALO - PAD_;
            const int hx   = w0 + lp % HALO - PAD_;
            f16x8 val = (f16x8)(_Float16)0.f;
            if ((unsigned)hy < (unsigned)H_ && (unsigned)hx < (unsigned)W_) {
                const unsigned short* src = (arr ? vb : kb)
                    + (size_t)(hy * W_ + hx) * CPG_ + half * 8;
                val = *(const f16x8*)src;
            }
            *(f16x8*)(&kvls[arr][lp * LP + half * 8]) = val;
        }
    }

    float qv[CPG_];
    #pragma unroll
    for (int c = 0; c < 8; ++c) { qv[c] = (float)q0[c]; qv[8 + c] = (float)q1[c]; }

    // rel score
    const bool useH = (g < 4);
    const float* rp = useH ? (rel_h + c0 * KW_) : (rel_w + (c0 - 64) * KW_);
    float rel[KW_];
    #pragma unroll
    for (int t = 0; t < KW_; ++t) {
        float r = 0.f;
        #pragma unroll
        for (int c = 0; c < CPG_; ++c) r += qv[c] * rp[c * KW_ + t];
        rel[t] = r;
    }

    __syncthreads();

    // scores: all 49 positions
    float s[KW_ * KW_];
    float smax = -1e30f;
    #pragma unroll
    for (int i = 0; i < KW_; ++i) {
        #pragma unroll
        for (int j = 0; j < KW_; ++j) {
            const unsigned short* kp = &kvls[0][((ph + i) * HALO + (pw + j)) * LP];
            const f16x8 k0 = *(const f16x8*)(kp);
            const f16x8 k1 = *(const f16x8*)(kp + 8);
            float sc = useH ? rel[i] : rel[j];
#ifdef HAVE_FDOT2
            #pragma unroll
            for (int t = 0; t < 4; ++t) {
                sc = __builtin_amdgcn_fdot2((h2){q0[2*t], q0[2*t+1]},
                                            (h2){k0[2*t], k0[2*t+1]}, sc, false);
                sc = __builtin_amdgcn_fdot2((h2){q1[2*t], q1[2*t+1]},
                                            (h2){k1[2*t], k1[2*t+1]}, sc, false);
            }
#else
            #pragma unroll
            for (int c = 0; c < 8; ++c)
                sc += qv[c] * (float)k0[c] + qv[8 + c] * (float)k1[c];
#endif
            s[i * KW_ + j] = sc;
            smax = fmaxf(smax, sc);
        }
    }

    // softmax
    float denom = 0.f;
    #pragma unroll
    for (int n = 0; n < KW_ * KW_; ++n) {
        s[n] = __expf(s[n] - smax);
        denom += s[n];
    }
    const float rdenom = 1.f / denom;

    // output = attn . V  -- packed f16x2 accumulation (a_j <= 1, den >= 1:
    // f16 round-off on the unnormalized acc is shrunk by rdenom at the end)
    f16x2 acch[8];
    #pragma unroll
    for (int c = 0; c < 8; ++c) acch[c] = (f16x2){(_Float16)0.f, (_Float16)0.f};

    #pragma unroll
    for (int i = 0; i < KW_; ++i) {
        #pragma unroll
        for (int j = 0; j < KW_; ++j) {
            const _Float16 ah = (_Float16)s[i * KW_ + j];
            const f16x2 av = {ah, ah};
            const unsigned short* vp = &kvls[1][((ph + i) * HALO + (pw + j)) * LP];
            const f16x8 v0 = *(const f16x8*)(vp);
            const f16x8 v1 = *(const f16x8*)(vp + 8);
            #pragma unroll
            for (int c = 0; c < 4; ++c) {
                const f16x2 p0v = {v0[2 * c], v0[2 * c + 1]};
                const f16x2 p1v = {v1[2 * c], v1[2 * c + 1]};
                acch[c]     += av * p0v;
                acch[4 + c] += av * p1v;
            }
        }
    }

    float* ob = out + ((size_t)b * C_ + c0) * HW_;
    #pragma unroll
    for (int c = 0; c < 8; ++c) {
        ob[(size_t)(2 * c)     * HW_ + pix] = (float)acch[c][0] * rdenom;
        ob[(size_t)(2 * c + 1) * HW_ + pix] = (float)acch[c][1] * rdenom;
    }
}

// ---------------------------------------------------------------------------
extern "C" void kernel_launch(void* const* d_in, const int* in_sizes, int n_in,
                              void* d_out, int out_size, void* d_ws, size_t ws_size,
                              hipStream_t stream) {
    const float* x     = (const float*)d_in[0];
    const float* Wq    = (const float*)d_in[1];
    const float* Wk    = (const float*)d_in[2];
    const float* Wv    = (const float*)d_in[3];
    const float* rel_h = (const float*)d_in[4];
    const float* rel_w = (const float*)d_in[5];
    unsigned short* ws = (unsigned short*)d_ws;  // fp16 qkv [3][B][G][4096][16] = 12 MB
    float* out = (float*)d_out;

    dim3 gA(HW_ / 64, B_, 6);
    proj_mfma<<<gA, 256, 0, stream>>>(x, Wq, Wk, Wv, ws);

    dim3 gB(16, G_, B_);
    attn_kernel<<<gB, 256, 0, stream>>>(ws, rel_h, rel_w, out);
}

// Round 17
// 31.526 us; speedup vs baseline: 1.1593x; 1.0103x over previous
//
#include <hip/hip_runtime.h>
#include <hip/hip_bf16.h>

#define B_   4
#define C_   128
#define H_   64
#define W_   64
#define HW_  4096
#define KW_  7
#define PAD_ 3
#define G_   8
#define CPG_ 16

#define CPAD 136   // f16 elems per LDS row in proj; row stride 272 B

// attn LDS geometry: 8x16 pixel tile, 2 threads/pixel (even/odd positions)
#define TSH   8
#define TSW   16
#define HLY   14          // TSH + 6
#define HLX   22          // TSW + 6
#define NHP2  (HLY*HLX)   // 308 halo pixels
#define LP    24          // ushorts per pixel (48 B, 16B-aligned)

typedef _Float16 f16x8 __attribute__((ext_vector_type(8)));
typedef _Float16 f16x2 __attribute__((ext_vector_type(2)));
typedef _Float16 h2    __attribute__((ext_vector_type(2)));
typedef float    f32x4 __attribute__((ext_vector_type(4)));

static __device__ __forceinline__ unsigned short f2h(float f) {
    _Float16 h = (_Float16)f;
    union { _Float16 h; unsigned short u; } cv; cv.h = h;
    return cv.u;
}

#if defined(__has_builtin)
#if __has_builtin(__builtin_amdgcn_fdot2)
#define HAVE_FDOT2 1
#endif
#endif

// ---------------------------------------------------------------------------
// Kernel A: fp16-MFMA 1x1 conv projections, O-HALF SPLIT (VERBATIM round-14).
// grid: (64 p-tiles, B, 6), block 256 (4 waves). LDS 34.8 KB -> 4 blocks/CU.
// Output: fp16, GROUP-PLANAR qkv16[m][b][g][pix][16] (pixel stride 32 B).
// ---------------------------------------------------------------------------
__global__ __launch_bounds__(256) void proj_mfma(
    const float* __restrict__ x,
    const float* __restrict__ Wq,
    const float* __restrict__ Wk,
    const float* __restrict__ Wv,
    unsigned short* __restrict__ qkv16)
{
    const int ptile = blockIdx.x;        // 0..63
    const int b     = blockIdx.y;
    const int mz    = blockIdx.z;        // 0..5
    const int m     = mz >> 1;
    const int oh    = mz & 1;
    const float* Wm = (m == 0) ? Wq : ((m == 1) ? Wk : Wv);
    const float* xb = x + (size_t)b * C_ * HW_;
    unsigned short* y = qkv16 + ((size_t)(m * B_ + b)) * HW_ * C_;
    const int p0  = ptile * 64;
    const int tid = threadIdx.x;

    __shared__ unsigned short wls[64 * CPAD];
    __shared__ unsigned short xls[64 * CPAD];

    #pragma unroll
    for (int it = 0; it < 8; ++it) {
        const int idx = tid + it * 256;
        const int o   = idx >> 5;
        const int c4  = (idx & 31) * 4;
        const float4 w4 = *(const float4*)(Wm + (size_t)(oh * 64 + o) * C_ + c4);
        ushort4 hh;
        hh.x = f2h(w4.x); hh.y = f2h(w4.y); hh.z = f2h(w4.z); hh.w = f2h(w4.w);
        *(ushort4*)(&wls[o * CPAD + c4]) = hh;
    }
    #pragma unroll
    for (int it = 0; it < 2; ++it) {
        const int idx = tid + it * 256;
        const int pq  = (idx & 15) * 4;
        const int cq  = (idx >> 4) * 4;
        const float* xp = xb + (size_t)cq * HW_ + p0 + pq;
        const float4 r0 = *(const float4*)(xp);
        const float4 r1 = *(const float4*)(xp + HW_);
        const float4 r2 = *(const float4*)(xp + 2 * HW_);
        const float4 r3 = *(const float4*)(xp + 3 * HW_);
        ushort4 hh;
        hh.x = f2h(r0.x); hh.y = f2h(r1.x); hh.z = f2h(r2.x); hh.w = f2h(r3.x);
        *(ushort4*)(&xls[(pq + 0) * CPAD + cq]) = hh;
        hh.x = f2h(r0.y); hh.y = f2h(r1.y); hh.z = f2h(r2.y); hh.w = f2h(r3.y);
        *(ushort4*)(&xls[(pq + 1) * CPAD + cq]) = hh;
        hh.x = f2h(r0.z); hh.y = f2h(r1.z); hh.z = f2h(r2.z); hh.w = f2h(r3.z);
        *(ushort4*)(&xls[(pq + 2) * CPAD + cq]) = hh;
        hh.x = f2h(r0.w); hh.y = f2h(r1.w); hh.z = f2h(r2.w); hh.w = f2h(r3.w);
        *(ushort4*)(&xls[(pq + 3) * CPAD + cq]) = hh;
    }
    __syncthreads();

    const int wv   = tid >> 6;
    const int lane = tid & 63;
    const int row  = lane & 15;
    const int kq   = lane >> 4;

    f32x4 acc[4];
    #pragma unroll
    for (int ot = 0; ot < 4; ++ot)
        acc[ot] = (f32x4){0.f, 0.f, 0.f, 0.f};

    #pragma unroll
    for (int ks = 0; ks < 4; ++ks) {
        const int cb = ks * 32 + kq * 8;
        const f16x8 bfrag = *(const f16x8*)(&xls[(wv * 16 + row) * CPAD + cb]);
        #pragma unroll
        for (int ot = 0; ot < 4; ++ot) {
            const f16x8 afrag = *(const f16x8*)(&wls[(ot * 16 + row) * CPAD + cb]);
            acc[ot] = __builtin_amdgcn_mfma_f32_16x16x32_f16(afrag, bfrag, acc[ot], 0, 0, 0);
        }
    }

    const int p = p0 + wv * 16 + row;
    #pragma unroll
    for (int ot = 0; ot < 4; ++ot) {
        const int got = oh * 4 + ot;
        ushort4 hh;
        hh.x = f2h(acc[ot][0]); hh.y = f2h(acc[ot][1]);
        hh.z = f2h(acc[ot][2]); hh.w = f2h(acc[ot][3]);
        *(ushort4*)(y + ((size_t)got * HW_ + p) * CPG_ + kq * 4) = hh;
    }
}

// ---------------------------------------------------------------------------
// attn helpers: per-position score and PV, compile-time (i,j)
// ---------------------------------------------------------------------------
static __device__ __forceinline__ float score_pos(
    const unsigned short* kls, const f16x8 q0, const f16x8 q1,
    int ph, int pw, int i, int j, float base)
{
    const unsigned short* kp = &kls[((ph + i) * HLX + (pw + j)) * LP];
    const f16x8 k0 = *(const f16x8*)(kp);
    const f16x8 k1 = *(const f16x8*)(kp + 8);
    float sc = base;
#ifdef HAVE_FDOT2
    #pragma unroll
    for (int t = 0; t < 4; ++t) {
        sc = __builtin_amdgcn_fdot2((h2){q0[2*t], q0[2*t+1]},
                                    (h2){k0[2*t], k0[2*t+1]}, sc, false);
        sc = __builtin_amdgcn_fdot2((h2){q1[2*t], q1[2*t+1]},
                                    (h2){k1[2*t], k1[2*t+1]}, sc, false);
    }
#else
    #pragma unroll
    for (int c = 0; c < 8; ++c)
        sc += (float)q0[c] * (float)k0[c] + (float)q1[c] * (float)k1[c];
#endif
    return sc;
}

static __device__ __forceinline__ void pv_pos(
    const unsigned short* vls, int ph, int pw, int i, int j,
    float a, f16x2* acch)
{
    const _Float16 ah = (_Float16)a;
    const f16x2 av = {ah, ah};
    const unsigned short* vp = &vls[((ph + i) * HLX + (pw + j)) * LP];
    const f16x8 v0 = *(const f16x8*)(vp);
    const f16x8 v1 = *(const f16x8*)(vp + 8);
    #pragma unroll
    for (int c = 0; c < 4; ++c) {
        const f16x2 p0v = {v0[2 * c], v0[2 * c + 1]};
        const f16x2 p1v = {v1[2 * c], v1[2 * c + 1]};
        acch[c]     += av * p0v;
        acch[4 + c] += av * p1v;
    }
}

// ---------------------------------------------------------------------------
// Kernel B: grouped 7x7 local attention, WINDOW-SPLIT 2 threads/pixel.
// 8x16 tile; threads 0..127 = even positions (25), 128..255 = odd (24);
// halves are separate waves (uniform branch). Flash-style 2-partition
// combine through padded LDS. grid: (32 tiles, G, B), block 256.
// ---------------------------------------------------------------------------
__global__ __launch_bounds__(256) void attn_kernel(
    const unsigned short* __restrict__ qkv16,
    const float* __restrict__ rel_h,   // [64][7]
    const float* __restrict__ rel_w,   // [64][7]
    float* __restrict__ out)           // [B][128][64][64]
{
    const int tile = blockIdx.x;        // 0..31
    const int g    = blockIdx.y;
    const int b    = blockIdx.z;
    const int h0   = (tile >> 2) * TSH;
    const int w0   = (tile & 3) * TSW;
    const int c0   = g * CPG_;

    __shared__ unsigned short kvls[2][NHP2 * LP];   // 29.6 KB
    __shared__ unsigned comb[128][11];              // 5.5 KB (pad 11: bank-free)

    const size_t gplane = (size_t)HW_ * CPG_;
    const size_t mplane = (size_t)B_ * G_ * gplane;
    const unsigned short* qb = qkv16              + ((size_t)b * G_ + g) * gplane;
    const unsigned short* kb = qkv16 + mplane     + ((size_t)b * G_ + g) * gplane;
    const unsigned short* vb = qkv16 + 2 * mplane + ((size_t)b * G_ + g) * gplane;

    const int tid = threadIdx.x;
    const int px  = tid & 127;
    const int hw  = tid >> 7;          // 0: even positions, 1: odd
    const int pw  = px & 15;
    const int ph  = px >> 4;           // 0..7
    const int pix = (h0 + ph) * W_ + (w0 + pw);

    // q fragment (each half loads its own copy; L1 hit)
    const f16x8 q0 = *(const f16x8*)(qb + (size_t)pix * CPG_);
    const f16x8 q1 = *(const f16x8*)(qb + (size_t)pix * CPG_ + 8);

    // stage K and V halo: 1232 x 16B chunks, coalesced, zero-fill OOB
    #pragma unroll
    for (int it = 0; it < 5; ++it) {
        const int idx = tid + it * 256;
        if (idx < 2 * NHP2 * 2) {
            const int arr  = (idx >= NHP2 * 2) ? 1 : 0;
            const int r    = idx - arr * NHP2 * 2;
            const int lp   = r >> 1;
            const int half = r & 1;
            const int yy   = lp / HLX;
            const int ww   = lp - yy * HLX;
            const int hy   = h0 + yy - PAD_;
            const int hx   = w0 + ww - PAD_;
            f16x8 val = (f16x8)(_Float16)0.f;
            if ((unsigned)hy < (unsigned)H_ && (unsigned)hx < (unsigned)W_) {
                const unsigned short* src = (arr ? vb : kb)
                    + (size_t)(hy * W_ + hx) * CPG_ + half * 8;
                val = *(const f16x8*)src;
            }
            *(f16x8*)(&kvls[arr][lp * LP + half * 8]) = val;
        }
    }

    // rel components
    const bool useH = (g < 4);
    const float* rp = useH ? (rel_h + c0 * KW_) : (rel_w + (c0 - 64) * KW_);
    float rel[KW_];
    {
        float qv[CPG_];
        #pragma unroll
        for (int c = 0; c < 8; ++c) { qv[c] = (float)q0[c]; qv[8 + c] = (float)q1[c]; }
        #pragma unroll
        for (int t = 0; t < KW_; ++t) {
            float r = 0.f;
            #pragma unroll
            for (int c = 0; c < CPG_; ++c) r += qv[c] * rp[c * KW_ + t];
            rel[t] = r;
        }
    }

    __syncthreads();

    const unsigned short* kls = kvls[0];
    const unsigned short* vls = kvls[1];

    float mloc, den = 0.f;
    f16x2 acch[8];
    #pragma unroll
    for (int c = 0; c < 8; ++c) acch[c] = (f16x2){(_Float16)0.f, (_Float16)0.f};

    if (hw == 0) {
        float s[25];
        float m = -1e30f;
        #pragma unroll
        for (int r = 0; r < 25; ++r) {
            const int n = 2 * r, i = n / 7, j = n % 7;
            s[r] = score_pos(kls, q0, q1, ph, pw, i, j, useH ? rel[i] : rel[j]);
            m = fmaxf(m, s[r]);
        }
        #pragma unroll
        for (int r = 0; r < 25; ++r) { s[r] = __expf(s[r] - m); den += s[r]; }
        #pragma unroll
        for (int r = 0; r < 25; ++r) {
            const int n = 2 * r, i = n / 7, j = n % 7;
            pv_pos(vls, ph, pw, i, j, s[r], acch);
        }
        mloc = m;
    } else {
        float s[24];
        float m = -1e30f;
        #pragma unroll
        for (int r = 0; r < 24; ++r) {
            const int n = 2 * r + 1, i = n / 7, j = n % 7;
            s[r] = score_pos(kls, q0, q1, ph, pw, i, j, useH ? rel[i] : rel[j]);
            m = fmaxf(m, s[r]);
        }
        #pragma unroll
        for (int r = 0; r < 24; ++r) { s[r] = __expf(s[r] - m); den += s[r]; }
        #pragma unroll
        for (int r = 0; r < 24; ++r) {
            const int n = 2 * r + 1, i = n / 7, j = n % 7;
            pv_pos(vls, ph, pw, i, j, s[r], acch);
        }
        mloc = m;
    }

    // half1 publishes its partials
    if (hw == 1) {
        comb[px][0] = __float_as_uint(mloc);
        comb[px][1] = __float_as_uint(den);
        #pragma unroll
        for (int c = 0; c < 8; ++c) {
            union { f16x2 v; unsigned u; } cv; cv.v = acch[c];
            comb[px][2 + c] = cv.u;
        }
    }
    __syncthreads();

    // half0 combines and writes
    if (hw == 0) {
        const float m1   = __uint_as_float(comb[px][0]);
        const float den1 = __uint_as_float(comb[px][1]);
        const float mC = fmaxf(mloc, m1);
        const float f0 = __expf(mloc - mC);
        const float f1 = __expf(m1 - mC);
        const float rden = 1.f / (den * f0 + den1 * f1);

        float* ob = out + ((size_t)b * C_ + c0) * HW_;
        #pragma unroll
        for (int c = 0; c < 8; ++c) {
            union { unsigned u; f16x2 v; } cv; cv.u = comb[px][2 + c];
            const f16x2 a1 = cv.v;
            ob[(size_t)(2 * c)     * HW_ + pix] =
                ((float)acch[c][0] * f0 + (float)a1[0] * f1) * rden;
            ob[(size_t)(2 * c + 1) * HW_ + pix] =
                ((float)acch[c][1] * f0 + (float)a1[1] * f1) * rden;
        }
    }
}

// ---------------------------------------------------------------------------
extern "C" void kernel_launch(void* const* d_in, const int* in_sizes, int n_in,
                              void* d_out, int out_size, void* d_ws, size_t ws_size,
                              hipStream_t stream) {
    const float* x     = (const float*)d_in[0];
    const float* Wq    = (const float*)d_in[1];
    const float* Wk    = (const float*)d_in[2];
    const float* Wv    = (const float*)d_in[3];
    const float* rel_h = (const float*)d_in[4];
    const float* rel_w = (const float*)d_in[5];
    unsigned short* ws = (unsigned short*)d_ws;  // fp16 qkv [3][B][G][4096][16] = 12 MB
    float* out = (float*)d_out;

    dim3 gA(HW_ / 64, B_, 6);
    proj_mfma<<<gA, 256, 0, stream>>>(x, Wq, Wk, Wv, ws);

    dim3 gB(32, G_, B_);
    attn_kernel<<<gB, 256, 0, stream>>>(ws, rel_h, rel_w, out);
}

// Round 18
// 31.516 us; speedup vs baseline: 1.1596x; 1.0003x over previous
//
#include <hip/hip_runtime.h>
#include <hip/hip_bf16.h>

#define B_   4
#define C_   128
#define H_   64
#define W_   64
#define HW_  4096
#define KW_  7
#define PAD_ 3
#define G_   8
#define CPG_ 16

#define CPAD 136   // f16 elems per LDS row in proj; row stride 272 B

// attn LDS geometry (round-6/10 proven)
#define TS    16
#define HALO  22
#define NHP   (HALO*HALO)
#define LP    24          // ushorts per pixel (48 B): balanced banks, 16B-aligned

typedef _Float16 f16x8 __attribute__((ext_vector_type(8)));
typedef _Float16 f16x2 __attribute__((ext_vector_type(2)));
typedef _Float16 h2    __attribute__((ext_vector_type(2)));
typedef float    f32x4 __attribute__((ext_vector_type(4)));

static __device__ __forceinline__ unsigned short f2h(float f) {
    _Float16 h = (_Float16)f;
    union { _Float16 h; unsigned short u; } cv; cv.h = h;
    return cv.u;
}

#if defined(__has_builtin)
#if __has_builtin(__builtin_amdgcn_fdot2)
#define HAVE_FDOT2 1
#endif
#endif

// ---------------------------------------------------------------------------
// Kernel A: fp16-MFMA 1x1 conv projections, 3-MATRIX FUSED + O-half split.
// Each block: 64 pixels x 64 out-channels x ALL THREE matrices.
// X^T staged ONCE (was 6x across the old z=6 grid); W halves double-buffered
// so the m+1 W stage overlaps the m MFMA phase. LDS 52.2 KB, grid 512 = 2/CU.
// Output: fp16, GROUP-PLANAR qkv16[m][b][g][pix][16] (pixel stride 32 B).
// grid: (64 p-tiles, B, 2 o-halves), block 256 (4 waves).
// ---------------------------------------------------------------------------
__global__ __launch_bounds__(256) void proj_mfma(
    const float* __restrict__ x,
    const float* __restrict__ Wq,
    const float* __restrict__ Wk,
    const float* __restrict__ Wv,
    unsigned short* __restrict__ qkv16)
{
    const int ptile = blockIdx.x;        // 0..63
    const int b     = blockIdx.y;
    const int oh    = blockIdx.z;        // 0..1: channels oh*64 .. oh*64+63
    const float* xb = x + (size_t)b * C_ * HW_;
    const int p0  = ptile * 64;
    const int tid = threadIdx.x;

    const float* Wms[3] = {Wq, Wk, Wv};

    __shared__ unsigned short wls[2][64 * CPAD];  // double-buffered W half
    __shared__ unsigned short xls[64 * CPAD];     // [p][c] f16 (transposed X)

    // ---- stage X^T ONCE: 4c x 4p micro-transpose blocks (2 iters) ----
    #pragma unroll
    for (int it = 0; it < 2; ++it) {
        const int idx = tid + it * 256;
        const int pq  = (idx & 15) * 4;
        const int cq  = (idx >> 4) * 4;
        const float* xp = xb + (size_t)cq * HW_ + p0 + pq;
        const float4 r0 = *(const float4*)(xp);
        const float4 r1 = *(const float4*)(xp + HW_);
        const float4 r2 = *(const float4*)(xp + 2 * HW_);
        const float4 r3 = *(const float4*)(xp + 3 * HW_);
        ushort4 hh;
        hh.x = f2h(r0.x); hh.y = f2h(r1.x); hh.z = f2h(r2.x); hh.w = f2h(r3.x);
        *(ushort4*)(&xls[(pq + 0) * CPAD + cq]) = hh;
        hh.x = f2h(r0.y); hh.y = f2h(r1.y); hh.z = f2h(r2.y); hh.w = f2h(r3.y);
        *(ushort4*)(&xls[(pq + 1) * CPAD + cq]) = hh;
        hh.x = f2h(r0.z); hh.y = f2h(r1.z); hh.z = f2h(r2.z); hh.w = f2h(r3.z);
        *(ushort4*)(&xls[(pq + 2) * CPAD + cq]) = hh;
        hh.x = f2h(r0.w); hh.y = f2h(r1.w); hh.z = f2h(r2.w); hh.w = f2h(r3.w);
        *(ushort4*)(&xls[(pq + 3) * CPAD + cq]) = hh;
    }

    // ---- stage W half for m=0 into wls[0] ----
    #pragma unroll
    for (int it = 0; it < 8; ++it) {
        const int idx = tid + it * 256;
        const int o   = idx >> 5;
        const int c4  = (idx & 31) * 4;
        const float4 w4 = *(const float4*)(Wq + (size_t)(oh * 64 + o) * C_ + c4);
        ushort4 hh;
        hh.x = f2h(w4.x); hh.y = f2h(w4.y); hh.z = f2h(w4.z); hh.w = f2h(w4.w);
        *(ushort4*)(&wls[0][o * CPAD + c4]) = hh;
    }
    __syncthreads();

    const int wv   = tid >> 6;     // wave id: owns 16 pixels
    const int lane = tid & 63;
    const int row  = lane & 15;
    const int kq   = lane >> 4;
    const int p    = p0 + wv * 16 + row;

    #pragma unroll
    for (int m = 0; m < 3; ++m) {
        // prefetch next W half into the other buffer (overlaps MFMAs below)
        if (m < 2) {
            const float* Wn = Wms[m + 1];
            unsigned short* dst = wls[(m + 1) & 1];
            #pragma unroll
            for (int it = 0; it < 8; ++it) {
                const int idx = tid + it * 256;
                const int o   = idx >> 5;
                const int c4  = (idx & 31) * 4;
                const float4 w4 = *(const float4*)(Wn + (size_t)(oh * 64 + o) * C_ + c4);
                ushort4 hh;
                hh.x = f2h(w4.x); hh.y = f2h(w4.y); hh.z = f2h(w4.z); hh.w = f2h(w4.w);
                *(ushort4*)(&dst[o * CPAD + c4]) = hh;
            }
        }

        // MFMA phase from wls[m&1]
        const unsigned short* wcur = wls[m & 1];
        f32x4 acc[4];
        #pragma unroll
        for (int ot = 0; ot < 4; ++ot)
            acc[ot] = (f32x4){0.f, 0.f, 0.f, 0.f};

        #pragma unroll
        for (int ks = 0; ks < 4; ++ks) {
            const int cb = ks * 32 + kq * 8;
            const f16x8 bfrag = *(const f16x8*)(&xls[(wv * 16 + row) * CPAD + cb]);
            #pragma unroll
            for (int ot = 0; ot < 4; ++ot) {
                const f16x8 afrag = *(const f16x8*)(&wcur[(ot * 16 + row) * CPAD + cb]);
                acc[ot] = __builtin_amdgcn_mfma_f32_16x16x32_f16(afrag, bfrag, acc[ot], 0, 0, 0);
            }
        }

        // store: lane holds D[o-local = ot*16 + kq*4 + reg][p]
        unsigned short* y = qkv16 + ((size_t)(m * B_ + b)) * HW_ * C_;
        #pragma unroll
        for (int ot = 0; ot < 4; ++ot) {
            const int got = oh * 4 + ot;
            ushort4 hh;
            hh.x = f2h(acc[ot][0]); hh.y = f2h(acc[ot][1]);
            hh.z = f2h(acc[ot][2]); hh.w = f2h(acc[ot][3]);
            *(ushort4*)(y + ((size_t)got * HW_ + p) * CPG_ + kq * 4) = hh;
        }

        if (m < 2) __syncthreads();   // next-W stage complete before next MFMA
    }
}

// ---------------------------------------------------------------------------
// Kernel B: grouped 7x7 local attention (VERBATIM round-14/16 best), fdot2
// scores, packed-f16 PV accumulation. grid: (16 tiles, G, B), block 256.
// ---------------------------------------------------------------------------
__global__ __launch_bounds__(256) void attn_kernel(
    const unsigned short* __restrict__ qkv16,
    const float* __restrict__ rel_h,   // [64][7]
    const float* __restrict__ rel_w,   // [64][7]
    float* __restrict__ out)           // [B][128][64][64]
{
    const int tile = blockIdx.x;
    const int g    = blockIdx.y;
    const int b    = blockIdx.z;
    const int h0   = (tile >> 2) * TS;
    const int w0   = (tile & 3) * TS;
    const int c0   = g * CPG_;

    __shared__ unsigned short kvls[2][NHP * LP];

    const size_t gplane = (size_t)HW_ * CPG_;
    const size_t mplane = (size_t)B_ * G_ * gplane;
    const unsigned short* qb = qkv16              + ((size_t)b * G_ + g) * gplane;
    const unsigned short* kb = qkv16 + mplane     + ((size_t)b * G_ + g) * gplane;
    const unsigned short* vb = qkv16 + 2 * mplane + ((size_t)b * G_ + g) * gplane;

    const int tid = threadIdx.x;
    const int pw  = tid & 15;
    const int ph  = tid >> 4;
    const int pix = (h0 + ph) * W_ + (w0 + pw);

    // q fragment first (independent of staging -> overlaps)
    const f16x8 q0 = *(const f16x8*)(qb + (size_t)pix * CPG_);
    const f16x8 q1 = *(const f16x8*)(qb + (size_t)pix * CPG_ + 8);

    // stage K and V halo: 1936 x 16B chunks, coalesced, zero-fill OOB
    #pragma unroll
    for (int it = 0; it < 8; ++it) {
        const int idx = tid + it * 256;
        if (idx < 2 * NHP * 2) {
            const int arr  = (idx >= NHP * 2) ? 1 : 0;
            const int r    = idx - arr * NHP * 2;
            const int lp   = r >> 1;
            const int half = r & 1;
            const int hy   = h0 + lp / HALO - PAD_;
            const int hx   = w0 + lp % HALO - PAD_;
            f16x8 val = (f16x8)(_Float16)0.f;
            if ((unsigned)hy < (unsigned)H_ && (unsigned)hx < (unsigned)W_) {
                const unsigned short* src = (arr ? vb : kb)
                    + (size_t)(hy * W_ + hx) * CPG_ + half * 8;
                val = *(const f16x8*)src;
            }
            *(f16x8*)(&kvls[arr][lp * LP + half * 8]) = val;
        }
    }

    float qv[CPG_];
    #pragma unroll
    for (int c = 0; c < 8; ++c) { qv[c] = (float)q0[c]; qv[8 + c] = (float)q1[c]; }

    // rel score
    const bool useH = (g < 4);
    const float* rp = useH ? (rel_h + c0 * KW_) : (rel_w + (c0 - 64) * KW_);
    float rel[KW_];
    #pragma unroll
    for (int t = 0; t < KW_; ++t) {
        float r = 0.f;
        #pragma unroll
        for (int c = 0; c < CPG_; ++c) r += qv[c] * rp[c * KW_ + t];
        rel[t] = r;
    }

    __syncthreads();

    // scores: all 49 positions
    float s[KW_ * KW_];
    float smax = -1e30f;
    #pragma unroll
    for (int i = 0; i < KW_; ++i) {
        #pragma unroll
        for (int j = 0; j < KW_; ++j) {
            const unsigned short* kp = &kvls[0][((ph + i) * HALO + (pw + j)) * LP];
            const f16x8 k0 = *(const f16x8*)(kp);
            const f16x8 k1 = *(const f16x8*)(kp + 8);
            float sc = useH ? rel[i] : rel[j];
#ifdef HAVE_FDOT2
            #pragma unroll
            for (int t = 0; t < 4; ++t) {
                sc = __builtin_amdgcn_fdot2((h2){q0[2*t], q0[2*t+1]},
                                            (h2){k0[2*t], k0[2*t+1]}, sc, false);
                sc = __builtin_amdgcn_fdot2((h2){q1[2*t], q1[2*t+1]},
                                            (h2){k1[2*t], k1[2*t+1]}, sc, false);
            }
#else
            #pragma unroll
            for (int c = 0; c < 8; ++c)
                sc += qv[c] * (float)k0[c] + qv[8 + c] * (float)k1[c];
#endif
            s[i * KW_ + j] = sc;
            smax = fmaxf(smax, sc);
        }
    }

    // softmax
    float denom = 0.f;
    #pragma unroll
    for (int n = 0; n < KW_ * KW_; ++n) {
        s[n] = __expf(s[n] - smax);
        denom += s[n];
    }
    const float rdenom = 1.f / denom;

    // output = attn . V  -- packed f16x2 accumulation (a_j <= 1, den >= 1:
    // f16 round-off on the unnormalized acc is shrunk by rdenom at the end)
    f16x2 acch[8];
    #pragma unroll
    for (int c = 0; c < 8; ++c) acch[c] = (f16x2){(_Float16)0.f, (_Float16)0.f};

    #pragma unroll
    for (int i = 0; i < KW_; ++i) {
        #pragma unroll
        for (int j = 0; j < KW_; ++j) {
            const _Float16 ah = (_Float16)s[i * KW_ + j];
            const f16x2 av = {ah, ah};
            const unsigned short* vp = &kvls[1][((ph + i) * HALO + (pw + j)) * LP];
            const f16x8 v0 = *(const f16x8*)(vp);
            const f16x8 v1 = *(const f16x8*)(vp + 8);
            #pragma unroll
            for (int c = 0; c < 4; ++c) {
                const f16x2 p0v = {v0[2 * c], v0[2 * c + 1]};
                const f16x2 p1v = {v1[2 * c], v1[2 * c + 1]};
                acch[c]     += av * p0v;
                acch[4 + c] += av * p1v;
            }
        }
    }

    float* ob = out + ((size_t)b * C_ + c0) * HW_;
    #pragma unroll
    for (int c = 0; c < 8; ++c) {
        ob[(size_t)(2 * c)     * HW_ + pix] = (float)acch[c][0] * rdenom;
        ob[(size_t)(2 * c + 1) * HW_ + pix] = (float)acch[c][1] * rdenom;
    }
}

// ---------------------------------------------------------------------------
extern "C" void kernel_launch(void* const* d_in, const int* in_sizes, int n_in,
                              void* d_out, int out_size, void* d_ws, size_t ws_size,
                              hipStream_t stream) {
    const float* x     = (const float*)d_in[0];
    const float* Wq    = (const float*)d_in[1];
    const float* Wk    = (const float*)d_in[2];
    const float* Wv    = (const float*)d_in[3];
    const float* rel_h = (const float*)d_in[4];
    const float* rel_w = (const float*)d_in[5];
    unsigned short* ws = (unsigned short*)d_ws;  // fp16 qkv [3][B][G][4096][16] = 12 MB
    float* out = (float*)d_out;

    dim3 gA(HW_ / 64, B_, 2);
    proj_mfma<<<gA, 256, 0, stream>>>(x, Wq, Wk, Wv, ws);

    dim3 gB(16, G_, B_);
    attn_kernel<<<gB, 256, 0, stream>>>(ws, rel_h, rel_w, out);
}